// Round 4
// baseline (1615.818 us; speedup 1.0000x reference)
//
#include <hip/hip_runtime.h>

// ---------------- problem constants (match reference) ----------------
#define Zl      384
#define MBr     46
#define NBc     68
#define DEG     7
#define K_INFO  8448
#define N_TX    25344
#define N_LDPC  (NBc * Zl)        // 26112
#define M_CHK   (MBr * Zl)        // 17664
#define E_EDGE  (MBr * DEG * Zl)  // 123648
#define BATCH   128
#define NUM_ITER 20
#define LLR_MAXF 20.0f
#define BCAP    32

// persistent-kernel geometry (R15)
#define NPG      96               // blocks per XCD group
#define NBLK     (NPG * 8)        // 768 blocks = 3 per CU uniform, big slack
#define CN_UNITS (M_CHK * 2)      // 35328 (node x quad) units per group-half
#define CN_PER_BLK (CN_UNITS / NPG) // 368
#define CN_TAIL  (CN_PER_BLK - 256) // 112
#define VN_UNITS (N_LDPC * 2)     // 52224

// NUMERICS CONTRACT (validated rounds 7-10, absmax 0.0625 vs 0.45):
//  - pure f32 end to end
//  - VN sum: accumulator starts at lch[v], then messages added in
//    ASCENDING edge-id order. DO NOT REORDER (other orders: 1.4-2.0).
//  - CN: two-min with strict < (first-argmin), sign via parity mask.
//  - CN state compression is EXACT (messages are +-min1/+-min2).
// Batch elements are independent -> any batch partitioning is order-safe.
// R15 arithmetic is BIT-IDENTICAL to verified R13 (scheduling-only change).
//
// PERF MODEL: R13 proved L2 residency (FETCH 24.6MB whole kernel) + %8
// XCD pinning, but 552 blocks -> 40 CUs carry 3 blocks (+39% phase time)
// and unbalanced vn ranges -> 811us. R14 (1024 blocks + XCD-local
// barrier atomics) failed -- suspected DEADLOCK: (a) 1024 = exact
// residency capacity, barrier needs all co-resident; (b) workgroup-scope
// atomics split across L2s if even one block lands off-%8. R15: 768
// blocks (3/CU uniform, ample slack), degree-balanced vn ranges, and
// barrier atomics back to AGENT (MALL) scope -- R13-proven to complete
// regardless of mapping. Data coherence still via XCD-local L2 +
// buffer_inv sc0 (L1-only invalidate; L2 stays resident).

// meta bits: [2:0]=amin, [9:3]=nm (neg mask), [10]=stot (parity)
// batch elem b: sector s=b>>3, lane-in-sector b&7; unit u=(node<<1)|ql

// ---------------------------------------------------------------------
// prep: lch[(s*N_LDPC + 2Z+n)*8 + (b&7)] = -clip(llr[b*N_TX + n])
// ---------------------------------------------------------------------
__global__ void prep_kernel(const float* __restrict__ llr, float* __restrict__ lch) {
    __shared__ float tile[32][33];
    const int n0 = blockIdx.x * 32, b0 = blockIdx.y * 32;
    const int tx = threadIdx.x, ty = threadIdx.y;
#pragma unroll
    for (int j = 0; j < 4; ++j) {
        float v = llr[(b0 + ty + 8 * j) * N_TX + n0 + tx];
        v = fminf(fmaxf(v, -LLR_MAXF), LLR_MAXF);
        tile[ty + 8 * j][tx] = -v;          // [b_local][n_local]
    }
    __syncthreads();
#pragma unroll
    for (int j = 0; j < 4; ++j) {
        const int b = b0 + tx;
        const int n = n0 + ty + 8 * j;
        lch[((size_t)(b >> 3) * N_LDPC + 2 * Zl + n) * 8 + (b & 7)] = tile[tx][ty + 8 * j];
    }
}

// ---------------------------------------------------------------------
// adjacency build, deterministic ascending base-edge order; plus vn
// cost-balanced block boundaries vb[NPG+1] (unit space, 64-rounded).
// badj[c*BCAP + slot] = sh | (d<<10) | (r<<13)   (sh<512, d<8, r<64)
// cadj[r*DEG + d]     = sh | (c<<10)             (cn-side, no col gather)
// ---------------------------------------------------------------------
__global__ void base_build_kernel(const int* __restrict__ col,
                                  int* __restrict__ bcount, int* __restrict__ badj,
                                  int* __restrict__ cadj, int* __restrict__ vb) {
    __shared__ int sc[MBr * DEG];
    __shared__ int ssh[MBr * DEG];
    const int t = threadIdx.x;
    if (t < MBr * DEG) {
        const int v0 = col[t * Zl];         // col[be*Z] = c*Z + shift
        const int c  = v0 / Zl;
        sc[t]  = c;
        ssh[t] = v0 - c * Zl;
        cadj[t] = ssh[t] | (sc[t] << 10);
    }
    if (t < NBc) bcount[t] = 0;
    __syncthreads();
    if (t < MBr * DEG) {
        const int c = sc[t];
        int slot = 0;
        for (int u = 0; u < t; ++u) slot += (sc[u] == c) ? 1 : 0;
        const int r = t / DEG, d = t - r * DEG;
        if (slot < BCAP) badj[c * BCAP + slot] = ssh[t] | (d << 10) | (r << 13);
        atomicAdd(&bcount[c], 1);           // order-independent (count only)
    }
    __syncthreads();
    if (t == 0) {
        // vn unit u = node*2+ql; node n in column c=n/Z costs cnt(c)+2.
        long long colpref[NBc + 1];
        colpref[0] = 0;
        for (int c = 0; c < NBc; ++c) {
            const int cost = min(bcount[c], BCAP) + 2;
            colpref[c + 1] = colpref[c] + (long long)cost * (2 * Zl);
        }
        const long long total = colpref[NBc];
        vb[0] = 0;
        int c = 0, prev = 0;
        for (int k = 1; k < NPG; ++k) {
            const long long target = (total * k) / NPG;
            while (colpref[c + 1] <= target) ++c;
            const int cost = min(bcount[c], BCAP) + 2;
            long long u = (long long)c * (2 * Zl) + (target - colpref[c]) / cost;
            int ui = (int)(u & ~63LL);      // 64-round for wave alignment
            if (ui < prev) ui = prev;       // monotone guard
            vb[k] = ui;
            prev = ui;
        }
        vb[NPG] = VN_UNITS;
    }
}

// ---------------------------------------------------------------------
// group barrier: NPG blocks of one XCD group. AGENT (MALL) scope atomics
// on a monotonic counter -- coherent whatever the block->XCD mapping, so
// a mapping violation cannot hang (R13-proven primitives). Barrier #nb
// waits for cnt == nb*NPG. Release: __syncthreads drains vmcnt (stores
// committed at L2; L1 is write-through). Acquire: buffer_inv sc0 --
// invalidate L1 ONLY; the local XCD L2, where all group data lives,
// stays resident (this is the whole point of the design).
// ---------------------------------------------------------------------
__device__ __forceinline__ void gsync(unsigned* cnt, unsigned target) {
    __syncthreads();
    if (threadIdx.x == 0) {
        const unsigned old = __hip_atomic_fetch_add(cnt, 1u, __ATOMIC_RELAXED,
                                                    __HIP_MEMORY_SCOPE_AGENT);
        if (old + 1u != target) {
            while (__hip_atomic_load(cnt, __ATOMIC_RELAXED,
                                     __HIP_MEMORY_SCOPE_AGENT) < target)
                __builtin_amdgcn_s_sleep(2);
        }
        asm volatile("buffer_inv sc0\n\t"
                     "s_waitcnt vmcnt(0)" ::: "memory");
    }
    __syncthreads();
}

// ---------------------------------------------------------------------
// CN unit body (identical arithmetic to verified R12/R13).
// ---------------------------------------------------------------------
template <bool FIRST>
__device__ __forceinline__ void cn_unit(const float* __restrict__ xin,
                                        float* __restrict__ state_f2,
                                        unsigned short* __restrict__ meta,
                                        const int* __restrict__ cadj,
                                        const int s, const int cn, const int ql) {
    const int r = cn / Zl;
    const int i = cn - r * Zl;

    const float4* xp = (const float4*)xin + (size_t)s * N_LDPC * 2;
    float4* sp = (float4*)state_f2 + ((size_t)s * M_CHK + cn) * 4 + ql * 2;
    ushort4* mp = (ushort4*)meta + ((size_t)s * M_CHK + cn) * 2 + ql;

    float omin1[4], omin2[4];
    int oamin[4]; unsigned onm[4], ostot[4];
    if (!FIRST) {
        const float4 sA = sp[0];
        const float4 sB = sp[1];
        omin1[0] = sA.x; omin2[0] = sA.y; omin1[1] = sA.z; omin2[1] = sA.w;
        omin1[2] = sB.x; omin2[2] = sB.y; omin1[3] = sB.z; omin2[3] = sB.w;
        const ushort4 mt = mp[0];
        const unsigned m4[4] = {mt.x, mt.y, mt.z, mt.w};
#pragma unroll
        for (int c = 0; c < 4; ++c) {
            oamin[c] = m4[c] & 7u;
            onm[c]   = (m4[c] >> 3) & 0x7Fu;
            ostot[c] = (m4[c] >> 10) & 1u;
        }
    }

    float min1[4] = {1e30f, 1e30f, 1e30f, 1e30f};
    float min2[4] = {1e30f, 1e30f, 1e30f, 1e30f};
    int   amin[4] = {0, 0, 0, 0};
    unsigned nm[4] = {0u, 0u, 0u, 0u};

#pragma unroll
    for (int d = 0; d < DEG; ++d) {
        const int pk = cadj[r * DEG + d];
        const int sh = pk & 0x3FF;
        const int c  = pk >> 10;
        int ii = i + sh; if (ii >= Zl) ii -= Zl;
        const int v = c * Zl + ii;
        const float4 xv = xp[(size_t)v * 2 + ql];
        float t[4] = {xv.x, xv.y, xv.z, xv.w};
        if (!FIRST) {
#pragma unroll
            for (int c2 = 0; c2 < 4; ++c2) {
                const float omag = (d == oamin[c2]) ? omin2[c2] : omin1[c2];
                const float mold = (ostot[c2] ^ ((onm[c2] >> d) & 1u)) ? -omag : omag;
                t[c2] -= mold;
            }
        }
#pragma unroll
        for (int c2 = 0; c2 < 4; ++c2) {
            const float mag = fabsf(t[c2]);
            nm[c2] |= (t[c2] < 0.f ? 1u : 0u) << d;
            if (mag < min1[c2]) { min2[c2] = min1[c2]; min1[c2] = mag; amin[c2] = d; }
            else if (mag < min2[c2]) { min2[c2] = mag; }
        }
    }

    float4 oA, oB;
    oA.x = min1[0]; oA.y = min2[0]; oA.z = min1[1]; oA.w = min2[1];
    oB.x = min1[2]; oB.y = min2[2]; oB.z = min1[3]; oB.w = min2[3];
    sp[0] = oA;
    sp[1] = oB;
    ushort4 mo;
    unsigned mv[4];
#pragma unroll
    for (int c = 0; c < 4; ++c)
        mv[c] = (unsigned)amin[c] | (nm[c] << 3) | ((unsigned)(__popc(nm[c]) & 1) << 10);
    mo.x = (unsigned short)mv[0]; mo.y = (unsigned short)mv[1];
    mo.z = (unsigned short)mv[2]; mo.w = (unsigned short)mv[3];
    mp[0] = mo;
}

// ---------------------------------------------------------------------
// VN unit body (identical arithmetic to verified R12/R13, LCH-FIRST).
// ---------------------------------------------------------------------
__device__ __forceinline__ void vn_unit(const float* __restrict__ lch,
                                        const float* __restrict__ state_f2,
                                        const unsigned short* __restrict__ meta,
                                        const int* __restrict__ bcount,
                                        const int* __restrict__ badj,
                                        float* __restrict__ x,
                                        const int s, const int v, const int ql) {
    const int c = v / Zl;
    const int j = v - c * Zl;
    const int cnt = min(bcount[c], BCAP);
    const int* bp = badj + c * BCAP;
    const float4* stp = (const float4*)state_f2 + (size_t)s * M_CHK * 4;
    const ushort4* mtp = (const ushort4*)meta + (size_t)s * M_CHK * 2;

    float4 sacc = ((const float4*)lch)[((size_t)s * N_LDPC + v) * 2 + ql];  // lch FIRST
    for (int k = 0; k < cnt; ++k) {
        const int pk = bp[k];
        const int sh = pk & 0x3FF;
        const int d  = (pk >> 10) & 7;
        const int r  = pk >> 13;
        int i = j - sh;
        if (i < 0) i += Zl;
        const int cnb = r * Zl + i;
        const float4 sA = stp[(size_t)cnb * 4 + ql * 2];
        const float4 sB = stp[(size_t)cnb * 4 + ql * 2 + 1];
        const ushort4 mt = mtp[(size_t)cnb * 2 + ql];
        const unsigned m4[4] = {mt.x, mt.y, mt.z, mt.w};
        const float mn1[4] = {sA.x, sA.z, sB.x, sB.z};
        const float mn2[4] = {sA.y, sA.w, sB.y, sB.w};
        float val[4];
#pragma unroll
        for (int cc = 0; cc < 4; ++cc) {
            const int   am  = m4[cc] & 7u;
            const unsigned nmv = (m4[cc] >> 3) & 0x7Fu;
            const unsigned st  = (m4[cc] >> 10) & 1u;
            const float mag = (d == am) ? mn2[cc] : mn1[cc];
            val[cc] = (st ^ ((nmv >> d) & 1u)) ? -mag : mag;
        }
        sacc.x += val[0]; sacc.y += val[1]; sacc.z += val[2]; sacc.w += val[3];
    }
    ((float4*)x)[((size_t)s * N_LDPC + v) * 2 + ql] = sacc;
}

// ---------------------------------------------------------------------
// persistent decode: 768 blocks = 3/CU uniform (ample residency slack;
// capacity at VGPR~60 is >=2x). blockIdx%8 = XCD group g; group g owns
// sectors g (h=0) and 8+g (h=1). No barrier at half boundary (disjoint).
// ---------------------------------------------------------------------
__global__ void __launch_bounds__(256, 4)
decode_persist(const float* __restrict__ lch, float* __restrict__ x,
               float* __restrict__ state, unsigned short* __restrict__ meta,
               const int* __restrict__ bcount, const int* __restrict__ badj,
               const int* __restrict__ cadj, const int* __restrict__ vb,
               unsigned* __restrict__ bar) {
    const int g  = blockIdx.x & 7;
    const int bg = blockIdx.x >> 3;            // 0..95 within group
    unsigned* cnt = bar + (size_t)g * 64;      // own 256B slab per group
    const int vu0 = vb[bg], vu1 = vb[bg + 1];  // degree-balanced vn range
    const int cu0 = bg * CN_PER_BLK;           // uniform cn range
    unsigned nb = 0;

    for (int h = 0; h < 2; ++h) {
        const int s = h * 8 + g;
        for (int t = 0; t < NUM_ITER; ++t) {
            // ---- CN phase: 368 units/block (pass of 256 + tail of 112) ----
            {
                const int u = cu0 + threadIdx.x;
                if (t == 0) {
                    cn_unit<true>(lch, state, meta, cadj, s, u >> 1, u & 1);
                    if (threadIdx.x < CN_TAIL) {
                        const int u2 = u + 256;
                        cn_unit<true>(lch, state, meta, cadj, s, u2 >> 1, u2 & 1);
                    }
                } else {
                    cn_unit<false>(x, state, meta, cadj, s, u >> 1, u & 1);
                    if (threadIdx.x < CN_TAIL) {
                        const int u2 = u + 256;
                        cn_unit<false>(x, state, meta, cadj, s, u2 >> 1, u2 & 1);
                    }
                }
            }
            ++nb; gsync(cnt, nb * NPG);
            // ---- VN phase: cost-balanced contiguous unit range ----
            for (int u = vu0 + threadIdx.x; u < vu1; u += 256)
                vn_unit(lch, state, meta, bcount, badj, x, s, u >> 1, u & 1);
            if (t != NUM_ITER - 1) { ++nb; gsync(cnt, nb * NPG); }
            // half boundary needs no sync: h=1 touches only sectors 8..15;
            // h=0's x writes are read only by out_kernel after kernel end.
        }
    }
}

// ---------------------------------------------------------------------
// output: out[b*K + k] = -x[(s*N_LDPC + k)*8 + (b&7)], k < K_INFO
// ---------------------------------------------------------------------
__global__ void out_kernel(const float* __restrict__ x, float* __restrict__ out) {
    __shared__ float tile[32][33];
    const int k0 = blockIdx.x * 32, b0 = blockIdx.y * 32;
    const int tx = threadIdx.x, ty = threadIdx.y;
#pragma unroll
    for (int j = 0; j < 4; ++j) {
        const int b = b0 + tx;
        const int k = k0 + ty + 8 * j;
        tile[ty + 8 * j][tx] = -x[((size_t)(b >> 3) * N_LDPC + k) * 8 + (b & 7)];
    }
    __syncthreads();
#pragma unroll
    for (int j = 0; j < 4; ++j) {
        out[(b0 + ty + 8 * j) * K_INFO + k0 + tx] = tile[tx][ty + 8 * j];
    }
}

// ---------------------------------------------------------------------
extern "C" void kernel_launch(void* const* d_in, const int* in_sizes, int n_in,
                              void* d_out, int out_size, void* d_ws, size_t ws_size,
                              hipStream_t stream) {
    const float* llr = (const float*)d_in[0];
    // d_in[1] = row (unused: row index derivable from edge-id structure)
    const int* col = (const int*)d_in[2];
    float* out = (float*)d_out;

    char* ws = (char*)d_ws;
    float* lch   = (float*)ws;                                   // 13,369,344 B
    float* x     = lch + (size_t)N_LDPC * BATCH;                 // 13,369,344 B
    float* state = x + (size_t)N_LDPC * BATCH;                   // 18,087,936 B
    unsigned short* meta = (unsigned short*)(state + (size_t)M_CHK * BATCH * 2); // 4,521,984 B
    int* bcount = (int*)(meta + (size_t)M_CHK * BATCH);          // 68*4
    int* badj   = bcount + NBc;                                  // 68*32*4
    int* cadj   = badj + NBc * BCAP;                             // 322*4
    int* vb     = cadj + MBr * DEG;                              // 97*4
    // barrier state: aligned 512B; 8 groups x 64 uints (256B slab each)
    size_t bar_off = (size_t)((char*)(vb + NPG + 1) - ws);
    bar_off = (bar_off + 511) & ~(size_t)511;
    unsigned* bar = (unsigned*)(ws + bar_off);
    // total ~49.4 MB

    // zero full lch: covers the punctured 2Z region in every sector
    hipMemsetAsync(lch, 0, (size_t)N_LDPC * BATCH * sizeof(float), stream);
    // barrier counters MUST be re-zeroed every launch (ws is poisoned)
    hipMemsetAsync(bar, 0, 8 * 64 * sizeof(unsigned), stream);

    prep_kernel<<<dim3(N_TX / 32, BATCH / 32), dim3(32, 8), 0, stream>>>(llr, lch);
    base_build_kernel<<<1, 512, 0, stream>>>(col, bcount, badj, cadj, vb);

    decode_persist<<<NBLK, 256, 0, stream>>>(lch, x, state, meta,
                                             bcount, badj, cadj, vb, bar);

    out_kernel<<<dim3(K_INFO / 32, BATCH / 32), dim3(32, 8), 0, stream>>>(x, out);
}

// Round 5
// 849.604 us; speedup vs baseline: 1.9018x; 1.9018x over previous
//
#include <hip/hip_runtime.h>

// ---------------- problem constants (match reference) ----------------
#define Zl      384
#define MBr     46
#define NBc     68
#define DEG     7
#define K_INFO  8448
#define N_TX    25344
#define N_LDPC  (NBc * Zl)        // 26112
#define M_CHK   (MBr * Zl)        // 17664
#define E_EDGE  (MBr * DEG * Zl)  // 123648
#define BATCH   128
#define NUM_ITER 20
#define LLR_MAXF 20.0f
#define BCAP    32

// persistent-kernel geometry (R16)
#define NPG      96               // blocks per XCD group
#define NBLK     (NPG * 8)        // 768 blocks = 3 per CU uniform, big slack
#define CN_UNITS (M_CHK * 2)      // 35328 (node x quad) units per group-half
#define CN_PER_BLK (CN_UNITS / NPG) // 368
#define CN_TAIL  (CN_PER_BLK - 256) // 112
#define VN_UNITS (N_LDPC * 2)     // 52224
#define FLAG_STRIDE 32            // dwords -> 128B per flag (own MALL line)

// NUMERICS CONTRACT (validated rounds 7-10, absmax 0.0625 vs 0.45):
//  - pure f32 end to end
//  - VN sum: accumulator starts at lch[v], then messages added in
//    ASCENDING edge-id order. DO NOT REORDER (other orders: 1.4-2.0).
//  - CN: two-min with strict < (first-argmin), sign via parity mask.
//  - CN state compression is EXACT (messages are +-min1/+-min2).
// Batch elements are independent -> any batch partitioning is order-safe.
// R16 arithmetic is BIT-IDENTICAL to verified R12/R13/R15.
//
// PERF MODEL: R15 measured 1456us with VALU-time ~300us == R13's ~295us
// -> ALL regression is barrier wait. Cause: spinners poll the SAME MALL
// line being atomically incremented (RMWs serialize ~100ns at the TCC
// atomic unit; 95 spinners/group multiply it -> ~14us/barrier x 78).
// R16 FIX: FLAG-ARRAY BARRIER, zero atomic RMW. Arrival = one relaxed
// agent store to an own 128B flag slot (96 parallel MALL lines). Master
// block's wave0 polls all 96 flags (2 loads/lane + __all), publishes a
// gen word; spinners poll read-only gen (R13-proven cheap). Acquire =
// buffer_inv sc0 (L1-only invalidate; XCD L2 -- where all group data
// lives -- stays resident). Monotonic everything: no reset race, no
// lost counts. L2 residency (FETCH ~27MB/kernel) + %8 pinning proven.

// meta bits: [2:0]=amin, [9:3]=nm (neg mask), [10]=stot (parity)
// batch elem b: sector s=b>>3, lane-in-sector b&7; unit u=(node<<1)|ql

// ---------------------------------------------------------------------
// prep: lch[(s*N_LDPC + 2Z+n)*8 + (b&7)] = -clip(llr[b*N_TX + n])
// ---------------------------------------------------------------------
__global__ void prep_kernel(const float* __restrict__ llr, float* __restrict__ lch) {
    __shared__ float tile[32][33];
    const int n0 = blockIdx.x * 32, b0 = blockIdx.y * 32;
    const int tx = threadIdx.x, ty = threadIdx.y;
#pragma unroll
    for (int j = 0; j < 4; ++j) {
        float v = llr[(b0 + ty + 8 * j) * N_TX + n0 + tx];
        v = fminf(fmaxf(v, -LLR_MAXF), LLR_MAXF);
        tile[ty + 8 * j][tx] = -v;          // [b_local][n_local]
    }
    __syncthreads();
#pragma unroll
    for (int j = 0; j < 4; ++j) {
        const int b = b0 + tx;
        const int n = n0 + ty + 8 * j;
        lch[((size_t)(b >> 3) * N_LDPC + 2 * Zl + n) * 8 + (b & 7)] = tile[tx][ty + 8 * j];
    }
}

// ---------------------------------------------------------------------
// adjacency build, deterministic ascending base-edge order; plus vn
// cost-balanced block boundaries vb[NPG+1] (unit space, 64-rounded).
// badj[c*BCAP + slot] = sh | (d<<10) | (r<<13)   (sh<512, d<8, r<64)
// cadj[r*DEG + d]     = sh | (c<<10)             (cn-side, no col gather)
// ---------------------------------------------------------------------
__global__ void base_build_kernel(const int* __restrict__ col,
                                  int* __restrict__ bcount, int* __restrict__ badj,
                                  int* __restrict__ cadj, int* __restrict__ vb) {
    __shared__ int sc[MBr * DEG];
    __shared__ int ssh[MBr * DEG];
    const int t = threadIdx.x;
    if (t < MBr * DEG) {
        const int v0 = col[t * Zl];         // col[be*Z] = c*Z + shift
        const int c  = v0 / Zl;
        sc[t]  = c;
        ssh[t] = v0 - c * Zl;
        cadj[t] = ssh[t] | (sc[t] << 10);
    }
    if (t < NBc) bcount[t] = 0;
    __syncthreads();
    if (t < MBr * DEG) {
        const int c = sc[t];
        int slot = 0;
        for (int u = 0; u < t; ++u) slot += (sc[u] == c) ? 1 : 0;
        const int r = t / DEG, d = t - r * DEG;
        if (slot < BCAP) badj[c * BCAP + slot] = ssh[t] | (d << 10) | (r << 13);
        atomicAdd(&bcount[c], 1);           // order-independent (count only)
    }
    __syncthreads();
    if (t == 0) {
        // vn unit u = node*2+ql; node n in column c=n/Z costs cnt(c)+2.
        long long colpref[NBc + 1];
        colpref[0] = 0;
        for (int c = 0; c < NBc; ++c) {
            const int cost = min(bcount[c], BCAP) + 2;
            colpref[c + 1] = colpref[c] + (long long)cost * (2 * Zl);
        }
        const long long total = colpref[NBc];
        vb[0] = 0;
        int c = 0, prev = 0;
        for (int k = 1; k < NPG; ++k) {
            const long long target = (total * k) / NPG;
            while (colpref[c + 1] <= target) ++c;
            const int cost = min(bcount[c], BCAP) + 2;
            long long u = (long long)c * (2 * Zl) + (target - colpref[c]) / cost;
            int ui = (int)(u & ~63LL);      // 64-round for wave alignment
            if (ui < prev) ui = prev;       // monotone guard
            vb[k] = ui;
            prev = ui;
        }
        vb[NPG] = VN_UNITS;
    }
}

// ---------------------------------------------------------------------
// FLAG-ARRAY group barrier (no atomic RMW anywhere).
// flags: NPG slots x 128B (own MALL line each). gen: one line.
// Arrival: relaxed agent store of monotone barrier# nb to own slot
//   (parallel across blocks -- nothing serializes).
// Master (bg==0): wave0 polls all 96 flags (2 loads/lane, __all),
//   then publishes gen = nb. Spinners poll read-only gen line.
// Release: __syncthreads before signaling drains vmcnt per wave ->
//   all data stores committed to (XCD-local) L2 before the flag store.
// Acquire: buffer_inv sc0 = invalidate L1 ONLY; local XCD L2, where
//   all group data lives, stays resident (the point of the design).
// Monotone flags/gen -> no reset race; a late block just delays gen.
// ---------------------------------------------------------------------
__device__ __forceinline__ void gsync(unsigned* __restrict__ flags,
                                      unsigned* __restrict__ gen,
                                      const int bg, const unsigned nb) {
    __syncthreads();
    if (bg == 0) {
        if (threadIdx.x == 0)
            __hip_atomic_store(flags, nb, __ATOMIC_RELAXED, __HIP_MEMORY_SCOPE_AGENT);
        if (threadIdx.x < 64) {
            const size_t i0 = (size_t)threadIdx.x * FLAG_STRIDE;
            const size_t i1 = (size_t)(64 + (threadIdx.x & 31)) * FLAG_STRIDE;
            for (;;) {
                const unsigned f0 = __hip_atomic_load(flags + i0, __ATOMIC_RELAXED,
                                                      __HIP_MEMORY_SCOPE_AGENT);
                const unsigned f1 = __hip_atomic_load(flags + i1, __ATOMIC_RELAXED,
                                                      __HIP_MEMORY_SCOPE_AGENT);
                if (__all(f0 >= nb && f1 >= nb)) break;
                __builtin_amdgcn_s_sleep(2);
            }
            if (threadIdx.x == 0)
                __hip_atomic_store(gen, nb, __ATOMIC_RELAXED, __HIP_MEMORY_SCOPE_AGENT);
        }
    } else if (threadIdx.x == 0) {
        __hip_atomic_store(flags + (size_t)bg * FLAG_STRIDE, nb, __ATOMIC_RELAXED,
                           __HIP_MEMORY_SCOPE_AGENT);
        while (__hip_atomic_load(gen, __ATOMIC_RELAXED, __HIP_MEMORY_SCOPE_AGENT) < nb)
            __builtin_amdgcn_s_sleep(8);
    }
    if (threadIdx.x == 0)
        asm volatile("buffer_inv sc0\n\ts_waitcnt vmcnt(0)" ::: "memory");
    __syncthreads();
}

// ---------------------------------------------------------------------
// CN unit body (identical arithmetic to verified R12/R13).
// ---------------------------------------------------------------------
template <bool FIRST>
__device__ __forceinline__ void cn_unit(const float* __restrict__ xin,
                                        float* __restrict__ state_f2,
                                        unsigned short* __restrict__ meta,
                                        const int* __restrict__ cadj,
                                        const int s, const int cn, const int ql) {
    const int r = cn / Zl;
    const int i = cn - r * Zl;

    const float4* xp = (const float4*)xin + (size_t)s * N_LDPC * 2;
    float4* sp = (float4*)state_f2 + ((size_t)s * M_CHK + cn) * 4 + ql * 2;
    ushort4* mp = (ushort4*)meta + ((size_t)s * M_CHK + cn) * 2 + ql;

    float omin1[4], omin2[4];
    int oamin[4]; unsigned onm[4], ostot[4];
    if (!FIRST) {
        const float4 sA = sp[0];
        const float4 sB = sp[1];
        omin1[0] = sA.x; omin2[0] = sA.y; omin1[1] = sA.z; omin2[1] = sA.w;
        omin1[2] = sB.x; omin2[2] = sB.y; omin1[3] = sB.z; omin2[3] = sB.w;
        const ushort4 mt = mp[0];
        const unsigned m4[4] = {mt.x, mt.y, mt.z, mt.w};
#pragma unroll
        for (int c = 0; c < 4; ++c) {
            oamin[c] = m4[c] & 7u;
            onm[c]   = (m4[c] >> 3) & 0x7Fu;
            ostot[c] = (m4[c] >> 10) & 1u;
        }
    }

    float min1[4] = {1e30f, 1e30f, 1e30f, 1e30f};
    float min2[4] = {1e30f, 1e30f, 1e30f, 1e30f};
    int   amin[4] = {0, 0, 0, 0};
    unsigned nm[4] = {0u, 0u, 0u, 0u};

#pragma unroll
    for (int d = 0; d < DEG; ++d) {
        const int pk = cadj[r * DEG + d];
        const int sh = pk & 0x3FF;
        const int c  = pk >> 10;
        int ii = i + sh; if (ii >= Zl) ii -= Zl;
        const int v = c * Zl + ii;
        const float4 xv = xp[(size_t)v * 2 + ql];
        float t[4] = {xv.x, xv.y, xv.z, xv.w};
        if (!FIRST) {
#pragma unroll
            for (int c2 = 0; c2 < 4; ++c2) {
                const float omag = (d == oamin[c2]) ? omin2[c2] : omin1[c2];
                const float mold = (ostot[c2] ^ ((onm[c2] >> d) & 1u)) ? -omag : omag;
                t[c2] -= mold;
            }
        }
#pragma unroll
        for (int c2 = 0; c2 < 4; ++c2) {
            const float mag = fabsf(t[c2]);
            nm[c2] |= (t[c2] < 0.f ? 1u : 0u) << d;
            if (mag < min1[c2]) { min2[c2] = min1[c2]; min1[c2] = mag; amin[c2] = d; }
            else if (mag < min2[c2]) { min2[c2] = mag; }
        }
    }

    float4 oA, oB;
    oA.x = min1[0]; oA.y = min2[0]; oA.z = min1[1]; oA.w = min2[1];
    oB.x = min1[2]; oB.y = min2[2]; oB.z = min1[3]; oB.w = min2[3];
    sp[0] = oA;
    sp[1] = oB;
    ushort4 mo;
    unsigned mv[4];
#pragma unroll
    for (int c = 0; c < 4; ++c)
        mv[c] = (unsigned)amin[c] | (nm[c] << 3) | ((unsigned)(__popc(nm[c]) & 1) << 10);
    mo.x = (unsigned short)mv[0]; mo.y = (unsigned short)mv[1];
    mo.z = (unsigned short)mv[2]; mo.w = (unsigned short)mv[3];
    mp[0] = mo;
}

// ---------------------------------------------------------------------
// VN unit body (identical arithmetic to verified R12/R13, LCH-FIRST).
// ---------------------------------------------------------------------
__device__ __forceinline__ void vn_unit(const float* __restrict__ lch,
                                        const float* __restrict__ state_f2,
                                        const unsigned short* __restrict__ meta,
                                        const int* __restrict__ bcount,
                                        const int* __restrict__ badj,
                                        float* __restrict__ x,
                                        const int s, const int v, const int ql) {
    const int c = v / Zl;
    const int j = v - c * Zl;
    const int cnt = min(bcount[c], BCAP);
    const int* bp = badj + c * BCAP;
    const float4* stp = (const float4*)state_f2 + (size_t)s * M_CHK * 4;
    const ushort4* mtp = (const ushort4*)meta + (size_t)s * M_CHK * 2;

    float4 sacc = ((const float4*)lch)[((size_t)s * N_LDPC + v) * 2 + ql];  // lch FIRST
    for (int k = 0; k < cnt; ++k) {
        const int pk = bp[k];
        const int sh = pk & 0x3FF;
        const int d  = (pk >> 10) & 7;
        const int r  = pk >> 13;
        int i = j - sh;
        if (i < 0) i += Zl;
        const int cnb = r * Zl + i;
        const float4 sA = stp[(size_t)cnb * 4 + ql * 2];
        const float4 sB = stp[(size_t)cnb * 4 + ql * 2 + 1];
        const ushort4 mt = mtp[(size_t)cnb * 2 + ql];
        const unsigned m4[4] = {mt.x, mt.y, mt.z, mt.w};
        const float mn1[4] = {sA.x, sA.z, sB.x, sB.z};
        const float mn2[4] = {sA.y, sA.w, sB.y, sB.w};
        float val[4];
#pragma unroll
        for (int cc = 0; cc < 4; ++cc) {
            const int   am  = m4[cc] & 7u;
            const unsigned nmv = (m4[cc] >> 3) & 0x7Fu;
            const unsigned st  = (m4[cc] >> 10) & 1u;
            const float mag = (d == am) ? mn2[cc] : mn1[cc];
            val[cc] = (st ^ ((nmv >> d) & 1u)) ? -mag : mag;
        }
        sacc.x += val[0]; sacc.y += val[1]; sacc.z += val[2]; sacc.w += val[3];
    }
    ((float4*)x)[((size_t)s * N_LDPC + v) * 2 + ql] = sacc;
}

// ---------------------------------------------------------------------
// persistent decode: 768 blocks = 3/CU uniform (ample residency slack).
// blockIdx%8 = XCD group g; group g owns sectors g (h=0) and 8+g (h=1).
// No barrier at half boundary (sectors disjoint).
// ---------------------------------------------------------------------
__global__ void __launch_bounds__(256, 4)
decode_persist(const float* __restrict__ lch, float* __restrict__ x,
               float* __restrict__ state, unsigned short* __restrict__ meta,
               const int* __restrict__ bcount, const int* __restrict__ badj,
               const int* __restrict__ cadj, const int* __restrict__ vb,
               unsigned* __restrict__ bar) {
    const int g  = blockIdx.x & 7;
    const int bg = blockIdx.x >> 3;            // 0..95 within group
    unsigned* gen   = bar + (size_t)g * 16;                 // own 64B line
    unsigned* flags = bar + 128 + (size_t)g * NPG * FLAG_STRIDE;
    const int vu0 = vb[bg], vu1 = vb[bg + 1];  // degree-balanced vn range
    const int cu0 = bg * CN_PER_BLK;           // uniform cn range
    unsigned nb = 0;

    for (int h = 0; h < 2; ++h) {
        const int s = h * 8 + g;
        for (int t = 0; t < NUM_ITER; ++t) {
            // ---- CN phase: 368 units/block (pass of 256 + tail of 112) ----
            {
                const int u = cu0 + threadIdx.x;
                if (t == 0) {
                    cn_unit<true>(lch, state, meta, cadj, s, u >> 1, u & 1);
                    if (threadIdx.x < CN_TAIL) {
                        const int u2 = u + 256;
                        cn_unit<true>(lch, state, meta, cadj, s, u2 >> 1, u2 & 1);
                    }
                } else {
                    cn_unit<false>(x, state, meta, cadj, s, u >> 1, u & 1);
                    if (threadIdx.x < CN_TAIL) {
                        const int u2 = u + 256;
                        cn_unit<false>(x, state, meta, cadj, s, u2 >> 1, u2 & 1);
                    }
                }
            }
            ++nb; gsync(flags, gen, bg, nb);
            // ---- VN phase: cost-balanced contiguous unit range ----
            for (int u = vu0 + threadIdx.x; u < vu1; u += 256)
                vn_unit(lch, state, meta, bcount, badj, x, s, u >> 1, u & 1);
            if (t != NUM_ITER - 1) { ++nb; gsync(flags, gen, bg, nb); }
            // half boundary needs no sync: h=1 touches only sectors 8..15;
            // h=0's x writes are read only by out_kernel after kernel end.
        }
    }
}

// ---------------------------------------------------------------------
// output: out[b*K + k] = -x[(s*N_LDPC + k)*8 + (b&7)], k < K_INFO
// ---------------------------------------------------------------------
__global__ void out_kernel(const float* __restrict__ x, float* __restrict__ out) {
    __shared__ float tile[32][33];
    const int k0 = blockIdx.x * 32, b0 = blockIdx.y * 32;
    const int tx = threadIdx.x, ty = threadIdx.y;
#pragma unroll
    for (int j = 0; j < 4; ++j) {
        const int b = b0 + tx;
        const int k = k0 + ty + 8 * j;
        tile[ty + 8 * j][tx] = -x[((size_t)(b >> 3) * N_LDPC + k) * 8 + (b & 7)];
    }
    __syncthreads();
#pragma unroll
    for (int j = 0; j < 4; ++j) {
        out[(b0 + ty + 8 * j) * K_INFO + k0 + tx] = tile[tx][ty + 8 * j];
    }
}

// ---------------------------------------------------------------------
extern "C" void kernel_launch(void* const* d_in, const int* in_sizes, int n_in,
                              void* d_out, int out_size, void* d_ws, size_t ws_size,
                              hipStream_t stream) {
    const float* llr = (const float*)d_in[0];
    // d_in[1] = row (unused: row index derivable from edge-id structure)
    const int* col = (const int*)d_in[2];
    float* out = (float*)d_out;

    char* ws = (char*)d_ws;
    float* lch   = (float*)ws;                                   // 13,369,344 B
    float* x     = lch + (size_t)N_LDPC * BATCH;                 // 13,369,344 B
    float* state = x + (size_t)N_LDPC * BATCH;                   // 18,087,936 B
    unsigned short* meta = (unsigned short*)(state + (size_t)M_CHK * BATCH * 2); // 4,521,984 B
    int* bcount = (int*)(meta + (size_t)M_CHK * BATCH);          // 68*4
    int* badj   = bcount + NBc;                                  // 68*32*4
    int* cadj   = badj + NBc * BCAP;                             // 322*4
    int* vb     = cadj + MBr * DEG;                              // 97*4
    // barrier state: aligned 512B; layout = [8 x gen line (64B)] then
    // [8 groups x 96 flags x 128B] -> 512B + 96KB
    size_t bar_off = (size_t)((char*)(vb + NPG + 1) - ws);
    bar_off = (bar_off + 511) & ~(size_t)511;
    unsigned* bar = (unsigned*)(ws + bar_off);
    const size_t bar_bytes = 128 * sizeof(unsigned)
                           + (size_t)8 * NPG * FLAG_STRIDE * sizeof(unsigned);
    // total ~49.5 MB

    // zero full lch: covers the punctured 2Z region in every sector
    hipMemsetAsync(lch, 0, (size_t)N_LDPC * BATCH * sizeof(float), stream);
    // barrier flags/gen MUST be re-zeroed every launch (ws is poisoned)
    hipMemsetAsync(bar, 0, bar_bytes, stream);

    prep_kernel<<<dim3(N_TX / 32, BATCH / 32), dim3(32, 8), 0, stream>>>(llr, lch);
    base_build_kernel<<<1, 512, 0, stream>>>(col, bcount, badj, cadj, vb);

    decode_persist<<<NBLK, 256, 0, stream>>>(lch, x, state, meta,
                                             bcount, badj, cadj, vb, bar);

    out_kernel<<<dim3(K_INFO / 32, BATCH / 32), dim3(32, 8), 0, stream>>>(x, out);
}